// Round 2
// baseline (2889.770 us; speedup 1.0000x reference)
//
#include <hip/hip_runtime.h>

typedef __bf16 bf16;
typedef bf16 bf16x8 __attribute__((ext_vector_type(8)));
typedef float f32x4 __attribute__((ext_vector_type(4)));

#define AS1 __attribute__((address_space(1)))
#define AS3 __attribute__((address_space(3)))

#define B_ 2048
#define T_ 80
#define E_ 100
#define H_ 512
#define TC_ 16              // time-chunk
#define NC_ (T_ / TC_)      // 5 chunks

// Layout: SEQ is TIME-MAJOR: seq[(t*B_ + b)*H_ + h]

__device__ __forceinline__ float fast_tanh(float x) {
  float e = exp2f(x * 2.8853900817779268f);  // e^{2x}
  return 1.f - 2.f * __builtin_amdgcn_rcpf(e + 1.f);
}

// dst[n*Kp + k] = k<K ? src[k*N + n] : 0   (transpose to [N][Kp], bf16, zero-pad K)
__global__ void convert_weight(const float* __restrict__ src, bf16* __restrict__ dst,
                               int K, int Kp, int N) {
  int idx = blockIdx.x * 256 + threadIdx.x;
  if (idx >= N * Kp) return;
  int n = idx / Kp, k = idx - n * Kp;
  float v = (k < K) ? src[(long)k * N + n] : 0.f;
  dst[idx] = (bf16)v;
}

// C[128-row tile] = A @ Bt^T for one time-chunk; A pre-offset to chunk start.
// A rows contiguous [TC_*B_], K = 512. Grid (TC_*B_/128, 4), 256 thr.
__global__ __launch_bounds__(256) void gemm_bf16(
    const bf16* __restrict__ A, const bf16* __restrict__ Bt, bf16* __restrict__ C, int K) {
  __shared__ bf16 As[128 * 32];
  __shared__ bf16 Bs[128 * 32];
  const int tid = threadIdx.x;
  const int wave = tid >> 6, lane = tid & 63;
  const int l = lane & 15, q = lane >> 4;
  const long m0 = (long)blockIdx.x * 128;
  const int n0 = blockIdx.y * 128;
  const int wm = (wave >> 1) * 64, wn = (wave & 1) * 64;

  f32x4 acc[4][4] = {};

  const int e0 = tid, e1 = 256 + tid;
  const int r0 = e0 >> 2, c0 = e0 & 3;
  const int r1 = e1 >> 2, c1 = e1 & 3;
  const int s0 = c0 ^ (r0 & 3) ^ ((r0 >> 2) & 3);
  const int s1 = c1 ^ (r1 & 3) ^ ((r1 >> 2) & 3);
  const int swr = q ^ (l & 3) ^ ((l >> 2) & 3);

  const bf16* A0 = A + (m0 + r0) * K + s0 * 8;
  const bf16* A1 = A + (m0 + r1) * K + s1 * 8;
  const bf16* B0 = Bt + (long)(n0 + r0) * K + s0 * 8;
  const bf16* B1 = Bt + (long)(n0 + r1) * K + s1 * 8;
  bf16* AsW0 = As + (wave * 64) * 8;
  bf16* AsW1 = As + (256 + wave * 64) * 8;
  bf16* BsW0 = Bs + (wave * 64) * 8;
  bf16* BsW1 = Bs + (256 + wave * 64) * 8;

  for (int k0 = 0; k0 < K; k0 += 32) {
    __builtin_amdgcn_global_load_lds((const AS1 void*)(A0 + k0), (AS3 void*)AsW0, 16, 0, 0);
    __builtin_amdgcn_global_load_lds((const AS1 void*)(A1 + k0), (AS3 void*)AsW1, 16, 0, 0);
    __builtin_amdgcn_global_load_lds((const AS1 void*)(B0 + k0), (AS3 void*)BsW0, 16, 0, 0);
    __builtin_amdgcn_global_load_lds((const AS1 void*)(B1 + k0), (AS3 void*)BsW1, 16, 0, 0);
    __syncthreads();
    bf16x8 af[4], bfm[4];
#pragma unroll
    for (int i = 0; i < 4; i++) {
      af[i]  = *(const bf16x8*)(As + (wm + i * 16 + l) * 32 + swr * 8);
      bfm[i] = *(const bf16x8*)(Bs + (wn + i * 16 + l) * 32 + swr * 8);
    }
#pragma unroll
    for (int i = 0; i < 4; i++)
#pragma unroll
      for (int j = 0; j < 4; j++)
        acc[i][j] = __builtin_amdgcn_mfma_f32_16x16x32_bf16(af[i], bfm[j], acc[i][j], 0, 0, 0);
    __syncthreads();
  }
#pragma unroll
  for (int i = 0; i < 4; i++)
#pragma unroll
    for (int j = 0; j < 4; j++)
#pragma unroll
      for (int r = 0; r < 4; r++)
        C[(m0 + wm + i * 16 + q * 4 + r) * (long)H_ + n0 + wn + j * 16 + l] =
            (bf16)acc[i][j][r];
}

// Layer-1 GEMM with fused embedding gather: C = emb[tokens] @ W1 (K padded to 128).
// Grid (TC_*16, 4): blockIdx.x -> (trow = x>>4, b0 = (x&15)*128), t = t0 + trow.
__global__ __launch_bounds__(256) void gemm1_embed(
    const int* __restrict__ tokens, const float* __restrict__ emb,
    const bf16* __restrict__ Bt, bf16* __restrict__ xwc, int t0) {
  __shared__ bf16 As[128 * 32];
  __shared__ bf16 Bs[128 * 32];
  __shared__ int stok[128];
  const int tid = threadIdx.x;
  const int wave = tid >> 6, lane = tid & 63;
  const int l = lane & 15, q = lane >> 4;
  const int trow = blockIdx.x >> 4;
  const int b0 = (blockIdx.x & 15) * 128;
  const int t = t0 + trow;
  const int n0 = blockIdx.y * 128;
  const int wm = (wave >> 1) * 64, wn = (wave & 1) * 64;
  const int K = 128;

  if (tid < 128) stok[tid] = tokens[(b0 + tid) * T_ + t];
  __syncthreads();

  f32x4 acc[4][4] = {};

  const int e0 = tid, e1 = 256 + tid;
  const int r0 = e0 >> 2, c0 = e0 & 3;
  const int r1 = e1 >> 2, c1 = e1 & 3;
  const int s0 = c0 ^ (r0 & 3) ^ ((r0 >> 2) & 3);
  const int s1 = c1 ^ (r1 & 3) ^ ((r1 >> 2) & 3);
  const int swr = q ^ (l & 3) ^ ((l >> 2) & 3);

  const bf16* B0 = Bt + (long)(n0 + r0) * K + s0 * 8;
  const bf16* B1 = Bt + (long)(n0 + r1) * K + s1 * 8;
  bf16* BsW0 = Bs + (wave * 64) * 8;
  bf16* BsW1 = Bs + (256 + wave * 64) * 8;

  // A staging ownership: row r = tid>>1, column-half hh = tid&1 (16 of 32 cols)
  const int ar = tid >> 1, hh = tid & 1;
  const int asw = (ar & 3) ^ ((ar >> 2) & 3);
  const float* er = emb + (long)stok[ar] * E_;

  for (int k0 = 0; k0 < K; k0 += 32) {
    __builtin_amdgcn_global_load_lds((const AS1 void*)(B0 + k0), (AS3 void*)BsW0, 16, 0, 0);
    __builtin_amdgcn_global_load_lds((const AS1 void*)(B1 + k0), (AS3 void*)BsW1, 16, 0, 0);
    bf16x8 v[2];
#pragma unroll
    for (int cch = 0; cch < 2; cch++) {
      int kb = k0 + hh * 16 + cch * 8;
#pragma unroll
      for (int j = 0; j < 8; j++) {
        int k = kb + j;
        v[cch][j] = (bf16)((k < E_) ? er[k] : 0.f);
      }
    }
    *(bf16x8*)(As + ar * 32 + ((2 * hh + 0) ^ asw) * 8) = v[0];
    *(bf16x8*)(As + ar * 32 + ((2 * hh + 1) ^ asw) * 8) = v[1];
    __syncthreads();
    bf16x8 af[4], bfm[4];
#pragma unroll
    for (int i = 0; i < 4; i++) {
      af[i]  = *(const bf16x8*)(As + (wm + i * 16 + l) * 32 + swr * 8);
      bfm[i] = *(const bf16x8*)(Bs + (wn + i * 16 + l) * 32 + swr * 8);
    }
#pragma unroll
    for (int i = 0; i < 4; i++)
#pragma unroll
      for (int j = 0; j < 4; j++)
        acc[i][j] = __builtin_amdgcn_mfma_f32_16x16x32_bf16(af[i], bfm[j], acc[i][j], 0, 0, 0);
    __syncthreads();
  }
  bf16* C = xwc + ((long)trow * B_ + b0) * H_;
#pragma unroll
  for (int i = 0; i < 4; i++)
#pragma unroll
    for (int j = 0; j < 4; j++)
#pragma unroll
      for (int r = 0; r < 4; r++)
        C[(long)(wm + i * 16 + q * 4 + r) * H_ + n0 + wn + j * 16 + l] =
            (bf16)acc[i][j][r];
}

// Recurrent chunk: block owns 16 batch rows for TC_ steps. Time-major seq.
// h_{t0-1} loaded from seq (written by previous chunk) unless first.
__global__ __launch_bounds__(256) void rnn_chunk(
    const bf16* __restrict__ xwc, const bf16* __restrict__ Ut,
    const float* __restrict__ bias, bf16* __restrict__ seq, int t0, int first) {
  __shared__ bf16 hls[16 * 520];  // +8 pad per row: conflict-free b128 reads
  const int tid = threadIdx.x;
  const int wave = tid >> 6, lane = tid & 63;
  const int l = lane & 15, q = lane >> 4;
  const int b0 = blockIdx.x * 16;

  if (first) {
    bf16x8 zv;
#pragma unroll
    for (int j = 0; j < 8; j++) zv[j] = (bf16)0.f;
    for (int i = tid * 8; i < 16 * 512; i += 256 * 8) {
      int m = i >> 9, n = i & 511;
      *(bf16x8*)(hls + m * 520 + n) = zv;
    }
  } else {
    const bf16* hsrc = seq + ((long)(t0 - 1) * B_ + b0) * H_;
    for (int i = tid * 8; i < 16 * 512; i += 256 * 8) {
      int m = i >> 9, n = i & 511;
      *(bf16x8*)(hls + m * 520 + n) = *(const bf16x8*)(hsrc + (long)m * H_ + n);
    }
  }

  float bb[8];
#pragma unroll
  for (int nt = 0; nt < 8; nt++) bb[nt] = bias[wave * 128 + nt * 16 + l];

  const bf16* hb = hls + l * 520 + q * 8;
  const bf16* Ub = Ut + (long)(wave * 128 + l) * H_ + q * 8;

  __syncthreads();

  for (int tl = 0; tl < TC_; tl++) {
    const bf16* xp = xwc + ((long)tl * B_ + b0 + q * 4) * H_ + wave * 128 + l;
    f32x4 acc[8];
#pragma unroll
    for (int nt = 0; nt < 8; nt++)
#pragma unroll
      for (int r = 0; r < 4; r++)
        acc[nt][r] = (float)xp[(long)r * H_ + nt * 16] + bb[nt];
    // acc += h_prev @ U  (K=512, software-pipelined U loads from L2)
    bf16x8 bfr[2][8];
#pragma unroll
    for (int nt = 0; nt < 8; nt++) bfr[0][nt] = *(const bf16x8*)(Ub + nt * 16 * H_);
#pragma unroll
    for (int kk = 0; kk < 16; kk++) {
      const int cur = kk & 1;
      if (kk < 15) {
#pragma unroll
        for (int nt = 0; nt < 8; nt++)
          bfr[cur ^ 1][nt] = *(const bf16x8*)(Ub + nt * 16 * H_ + (kk + 1) * 32);
      }
      bf16x8 a = *(const bf16x8*)(hb + kk * 32);
#pragma unroll
      for (int nt = 0; nt < 8; nt++)
        acc[nt] = __builtin_amdgcn_mfma_f32_16x16x32_bf16(a, bfr[cur][nt], acc[nt], 0, 0, 0);
    }
    __syncthreads();  // all hls reads for this step complete
    bf16* sp = seq + ((long)(t0 + tl) * B_ + b0 + q * 4) * H_ + wave * 128 + l;
#pragma unroll
    for (int nt = 0; nt < 8; nt++) {
      int n = wave * 128 + nt * 16 + l;
#pragma unroll
      for (int r = 0; r < 4; r++) {
        bf16 hv = (bf16)fast_tanh(acc[nt][r]);
        hls[(q * 4 + r) * 520 + n] = hv;
        sp[(long)r * H_ + nt * 16] = hv;
      }
    }
    __syncthreads();  // hls updated before next step's reads
  }
}

// out[b] = sigmoid(dot(seq[(T-1)*B + b, :], Wo) + bo); one wave per row
__global__ __launch_bounds__(256) void head_kernel(
    const bf16* __restrict__ seq, const float* __restrict__ Wo,
    const float* __restrict__ bo, float* __restrict__ out) {
  int wave = threadIdx.x >> 6, lane = threadIdx.x & 63;
  int row = blockIdx.x * 4 + wave;
  const bf16* p = seq + ((long)(T_ - 1) * B_ + row) * H_ + lane * 8;
  bf16x8 v = *(const bf16x8*)p;
  float s = 0.f;
#pragma unroll
  for (int i = 0; i < 8; i++) s += (float)v[i] * Wo[lane * 8 + i];
#pragma unroll
  for (int off = 32; off; off >>= 1) s += __shfl_down(s, off, 64);
  if (lane == 0) {
    float x = s + bo[0];
    out[row] = 1.f / (1.f + exp2f(-x * 1.44269504088896f));
  }
}

extern "C" void kernel_launch(void* const* d_in, const int* in_sizes, int n_in,
                              void* d_out, int out_size, void* d_ws, size_t ws_size,
                              hipStream_t stream) {
  (void)in_sizes; (void)n_in; (void)out_size; (void)ws_size;
  const int*   tokens = (const int*)d_in[0];
  const float* emb = (const float*)d_in[1];
  const float* W1 = (const float*)d_in[2];
  const float* U1 = (const float*)d_in[3];
  const float* b1 = (const float*)d_in[4];
  const float* W2 = (const float*)d_in[5];
  const float* U2 = (const float*)d_in[6];
  const float* b2 = (const float*)d_in[7];
  const float* W3 = (const float*)d_in[8];
  const float* U3 = (const float*)d_in[9];
  const float* b3 = (const float*)d_in[10];
  const float* W4 = (const float*)d_in[11];
  const float* U4 = (const float*)d_in[12];
  const float* b4 = (const float*)d_in[13];
  const float* Wo = (const float*)d_in[14];
  const float* bo = (const float*)d_in[15];
  float* out = (float*)d_out;

  // ws: SEQ [T_*B_, H_] bf16 (time-major, in-place across layers) | XWC [TC_*B_, H_] | weights
  char* w = (char*)d_ws;
  const size_t SEQ_BYTES = (size_t)T_ * B_ * H_ * 2;   // 160 MB
  const size_t XWC_BYTES = (size_t)TC_ * B_ * H_ * 2;  // 32 MB
  bf16* SEQ = (bf16*)w;
  bf16* XWC = (bf16*)(w + SEQ_BYTES);
  bf16* W1t = (bf16*)(w + SEQ_BYTES + XWC_BYTES);
  bf16* U1t = W1t + 512 * 128;
  bf16* W2t = U1t + 512 * 512;
  bf16* U2t = W2t + 512 * 512;
  bf16* W3t = U2t + 512 * 512;
  bf16* U3t = W3t + 512 * 512;
  bf16* W4t = U3t + 512 * 512;
  bf16* U4t = W4t + 512 * 512;

  convert_weight<<<(512 * 128) / 256, 256, 0, stream>>>(W1, W1t, 100, 128, 512);
  convert_weight<<<(512 * 512) / 256, 256, 0, stream>>>(U1, U1t, 512, 512, 512);
  convert_weight<<<(512 * 512) / 256, 256, 0, stream>>>(W2, W2t, 512, 512, 512);
  convert_weight<<<(512 * 512) / 256, 256, 0, stream>>>(U2, U2t, 512, 512, 512);
  convert_weight<<<(512 * 512) / 256, 256, 0, stream>>>(W3, W3t, 512, 512, 512);
  convert_weight<<<(512 * 512) / 256, 256, 0, stream>>>(U3, U3t, 512, 512, 512);
  convert_weight<<<(512 * 512) / 256, 256, 0, stream>>>(W4, W4t, 512, 512, 512);
  convert_weight<<<(512 * 512) / 256, 256, 0, stream>>>(U4, U4t, 512, 512, 512);

  const bf16* Wt[4] = {W1t, W2t, W3t, W4t};
  const bf16* Us[4] = {U1t, U2t, U3t, U4t};
  const float* bs[4] = {b1, b2, b3, b4};

  for (int layer = 0; layer < 4; layer++) {
    for (int c = 0; c < NC_; c++) {
      if (layer == 0)
        gemm1_embed<<<dim3(TC_ * 16, 4), 256, 0, stream>>>(tokens, emb, W1t, XWC, c * TC_);
      else
        gemm_bf16<<<dim3(TC_ * B_ / 128, 4), 256, 0, stream>>>(
            SEQ + (size_t)c * TC_ * B_ * H_, Wt[layer], XWC, H_);
      rnn_chunk<<<B_ / 16, 256, 0, stream>>>(XWC, Us[layer], bs[layer], SEQ, c * TC_, c == 0);
    }
  }

  head_kernel<<<B_ / 4, 256, 0, stream>>>(SEQ, Wo, bo, out);
}